// Round 9
// baseline (1635.686 us; speedup 1.0000x reference)
//
#include <hip/hip_runtime.h>
#include <hip/hip_bf16.h>

// ---------------------------------------------------------------------------
// Round 8: gemm PROBE + redesign. Pool measured at BW floor (33.5us) in R7.
// New gemm: 256 blocks x 8 waves, block = 16 cols x full K, in-block split-K
// (wave w = K-slice of 256), LDS reduction, fused bias, direct Y write.
// gemm amplified x32 (opaque zero dep) for top-5 visibility; all else x1.
// ---------------------------------------------------------------------------

#define NNODES 192
#define CFEAT  2048

typedef __attribute__((ext_vector_type(8))) short bf16x8;
typedef __attribute__((ext_vector_type(4))) float f32x4;

__device__ inline unsigned f2bf(float f) {                 // RNE f32 -> bf16
    union { float f; unsigned u; } v; v.f = f;
    unsigned u = v.u;
    u += 0x7FFFu + ((u >> 16) & 1u);
    return u >> 16;
}

// ---- 1. Global average pool (measured: ~33.5us, ~6TB/s effective = at floor)
__global__ __launch_bounds__(256) void pool_kernel(const float* __restrict__ F,
                                                   float* __restrict__ POOL,
                                                   unsigned short* __restrict__ POOLB) {
    int wave = threadIdx.x >> 6, lane = threadIdx.x & 63;
    #pragma unroll
    for (int it = 0; it < 12; ++it) {
        int dr = blockIdx.x * 4 + wave + it * 16384;   // [0, 196608)
        int r0 = dr * 2;
        int n = r0 >> 11, c0 = r0 & 2047;
        int p = n >> 5, b = n & 31;                    // n = p*32 + b
        const float* src = F + (((size_t)b * 12288 + (size_t)p * 2048 + c0) << 7);
        float4 v = *(const float4*)(src + (lane << 2));
        float acc = (v.x + v.y) + (v.z + v.w);
        acc += __shfl_down(acc, 16);
        acc += __shfl_down(acc, 8);
        acc += __shfl_down(acc, 4);
        acc += __shfl_down(acc, 2);
        acc += __shfl_down(acc, 1);
        if ((lane & 31) == 0) {
            int r = r0 + (lane >> 5);
            float m = acc * (1.0f / 128.0f);
            POOL[r] = m;
            POOLB[r] = (unsigned short)f2bf(m);
        }
    }
}

// ---- 2. GEMM v3 (x32 probe reps): Y[192][4096] = X @ [Wl|Wr] + bias.
// grid 256: block ct -> flat cols [ct*16, ct*16+16).  8 waves; wave w owns
// K in [w*256,(w+1)*256) -> partial [192][16]; LDS-reduce over waves; Y write.
// Per step: 12 A-frags (bf16x8 direct), 8 strided W dwords -> cvt, 12 MFMA.
__global__ __launch_bounds__(512) void gemm_kernel(
    const unsigned short* __restrict__ X,    // bf16 [192][2048]
    const float* __restrict__ WL,            // fp32 [4][2048][512] (layer slice)
    const float* __restrict__ WR,
    const float* __restrict__ BL,            // fp32 [2048] flat (layer slice)
    const float* __restrict__ BR,
    float* __restrict__ Y) {                 // fp32 [192][4096]
    __shared__ float red[8 * 192 * 18];      // stride 18: ~2-way banks, 110 KB

    int ct = blockIdx.x;                     // [0,256)
    int t = threadIdx.x, w = t >> 6, l = t & 63;
    int lr = l & 15, lg = l >> 4;

    int ncol = ct << 4;                      // flat col base [0,4096)
    bool sideR = ncol >= 2048;
    int scol = ncol & 2047;                  // head*512 + dcol0
    const float* Wb = (sideR ? WR : WL)
                    + (size_t)(scol >> 9) * (2048 * 512) + (scol & 511) + lr;
    const float* Bb = (sideR ? BR : BL) + scol;
    int kw = w << 8;                         // wave K-base

    int dep = 0;
    #pragma unroll 1
    for (int rep = 0; rep < 32; ++rep) {
        __syncthreads();                     // protect red[] across reps
        const unsigned short* Xp = X + (size_t)lr * 2048 + kw + lg * 8 + dep;
        const float* Wp = Wb + (size_t)(kw + lg * 8) * 512 + dep;

        f32x4 acc[12];
        #pragma unroll
        for (int fi = 0; fi < 12; ++fi) acc[fi] = {0.f, 0.f, 0.f, 0.f};

        bf16x8 aC[12];
        float  bC[8];
        #pragma unroll
        for (int fi = 0; fi < 12; ++fi)
            aC[fi] = *(const bf16x8*)(Xp + (size_t)fi * 16 * 2048);
        #pragma unroll
        for (int j = 0; j < 8; ++j) bC[j] = Wp[(size_t)j * 512];

        #pragma unroll
        for (int s = 0; s < 8; ++s) {
            bf16x8 aN[12];
            float  bN[8];
            if (s < 7) {                     // depth-2 prefetch
                const unsigned short* xp = Xp + (s + 1) * 32;
                const float* wp = Wp + (size_t)(s + 1) * 32 * 512;
                #pragma unroll
                for (int fi = 0; fi < 12; ++fi)
                    aN[fi] = *(const bf16x8*)(xp + (size_t)fi * 16 * 2048);
                #pragma unroll
                for (int j = 0; j < 8; ++j) bN[j] = wp[(size_t)j * 512];
            }
            bf16x8 bfr;
            #pragma unroll
            for (int j = 0; j < 8; ++j)
                bfr[j] = (short)__builtin_bit_cast(unsigned short,
                              __float2bfloat16(bC[j]));
            #pragma unroll
            for (int fi = 0; fi < 12; ++fi)
                acc[fi] = __builtin_amdgcn_mfma_f32_16x16x32_bf16(
                              aC[fi], bfr, acc[fi], 0, 0, 0);
            if (s < 7) {
                #pragma unroll
                for (int fi = 0; fi < 12; ++fi) aC[fi] = aN[fi];
                #pragma unroll
                for (int j = 0; j < 8; ++j) bC[j] = bN[j];
            }
        }

        // stash partials: D row = lg*4 + reg (frag fi base 16*fi), col = lr
        #pragma unroll
        for (int fi = 0; fi < 12; ++fi)
            #pragma unroll
            for (int j = 0; j < 4; ++j)
                red[(w * 192 + fi * 16 + lg * 4 + j) * 18 + lr] = acc[fi][j];
        __syncthreads();

        // reduce 8 partials -> Y (+bias); 3072 outputs / 512 threads
        #pragma unroll
        for (int e = 0; e < 6; ++e) {
            int idx = t + e * 512;
            int row = idx >> 4, col = idx & 15;
            float s = 0.f;
            #pragma unroll
            for (int ww = 0; ww < 8; ++ww)
                s += red[(ww * 192 + row) * 18 + col];
            Y[(size_t)row * 4096 + ncol + col] = s + Bb[col];
        }
        dep = (acc[0][0] > 1e30f) ? 1 : 0;   // always 0, opaque serializer
    }
}

// ---- 3. Attention per (instance g, head h). Y: [192][4096], xl 0..2047,
// xr 2048..4095 (bias already in Y).
template <int LAYER>
__global__ __launch_bounds__(256) void attn_kernel(
    const float* __restrict__ Y,
    const float* __restrict__ ATT,
    const float* __restrict__ GBIAS,
    const int* __restrict__ NPS,
    const float* __restrict__ POOL,
    float* __restrict__ OUTF,
    unsigned short* __restrict__ OUTB) {
    __shared__ float xls[6][512];
    __shared__ float xrs[6][512];
    __shared__ float atts[512];
    __shared__ float s_sm[6][6];
    __shared__ float alpha[6][6];

    int g = blockIdx.x, h = blockIdx.y;
    int tid = threadIdx.x;
    int cnt = NPS[g];

    for (int idx = tid; idx < 6 * 512; idx += 256) {
        int q = idx >> 9, d = idx & 511;
        size_t off = (size_t)(g * 6 + q) * 4096 + h * 512 + d;
        xls[q][d] = Y[off];
        xrs[q][d] = Y[off + 2048];
    }
    for (int d = tid; d < 512; d += 256) atts[d] = ATT[h * 512 + d];
    __syncthreads();

    int wv = tid >> 6, lane = tid & 63;
    for (int p = wv; p < 36; p += 4) {
        int i = p / 6, j = p % 6;
        float acc = 0.f;
        #pragma unroll
        for (int u = 0; u < 8; ++u) {
            int d = lane + u * 64;
            float v = xrs[i][d] + xls[j][d];
            v = (v >= 0.f) ? v : 0.2f * v;
            acc = fmaf(atts[d], v, acc);
        }
        #pragma unroll
        for (int off = 32; off; off >>= 1) acc += __shfl_down(acc, off);
        if (lane == 0) s_sm[i][j] = acc;
    }
    __syncthreads();

    if (tid < 6) {
        int i = tid;
        bool iv = i < cnt;
        float mx;
        if (iv) {
            mx = -1e30f;
            for (int j = 0; j < cnt; ++j) mx = fmaxf(mx, s_sm[i][j]);
        } else {
            mx = s_sm[i][i];
        }
        float e[6], sum = 0.f;
        for (int j = 0; j < 6; ++j) {
            bool nb = iv ? (j < cnt) : (j == i);
            e[j] = nb ? expf(s_sm[i][j] - mx) : 0.f;
            sum += e[j];
        }
        float inv = 1.f / sum;
        for (int j = 0; j < 6; ++j) alpha[i][j] = e[j] * inv;
    }
    __syncthreads();

    for (int idx = tid; idx < 6 * 512; idx += 256) {
        int q = idx >> 9, d = idx & 511;
        float acc = 0.f;
        #pragma unroll
        for (int j = 0; j < 6; ++j) acc = fmaf(alpha[q][j], xls[j][d], acc);
        int col = h * 512 + d;
        size_t off = (size_t)(g * 6 + q) * 2048 + col;
        float v = acc + GBIAS[col];
        if (LAYER == 0) {
            v = (v > 0.f) ? v : expm1f(v);
            OUTB[off] = (unsigned short)f2bf(v);
        } else {
            OUTF[off] = v + POOL[off];
        }
    }
}

// ---- 4. Part-mean + BN
__global__ __launch_bounds__(256) void final_kernel(
    const float* __restrict__ GF, const float* __restrict__ GAMMA,
    const float* __restrict__ MEAN, const float* __restrict__ VAR,
    float* __restrict__ OUTP) {
    int idx = blockIdx.x * 256 + threadIdx.x;   // [0, 65536)
    int c = idx & 2047, b = idx >> 11;
    float acc = 0.f;
    #pragma unroll
    for (int p = 0; p < 6; ++p) acc += GF[(size_t)(p * 32 + b) * 2048 + c];
    acc *= (1.f / 6.f);
    OUTP[idx] = GAMMA[c] * (acc - MEAN[c]) * rsqrtf(VAR[c] + 1e-5f);
}

extern "C" void kernel_launch(void* const* d_in, const int* in_sizes, int n_in,
                              void* d_out, int out_size, void* d_ws, size_t ws_size,
                              hipStream_t stream) {
    const float* F     = (const float*)d_in[0];
    const int*   nps   = (const int*)d_in[1];
    const float* Wl    = (const float*)d_in[2];
    const float* bl    = (const float*)d_in[3];
    const float* Wr    = (const float*)d_in[4];
    const float* br    = (const float*)d_in[5];
    const float* att   = (const float*)d_in[6];
    const float* gb    = (const float*)d_in[7];
    const float* gamma = (const float*)d_in[8];
    const float* mean  = (const float*)d_in[9];
    const float* var   = (const float*)d_in[10];
    float* out = (float*)d_out;
    float* wsf = (float*)d_ws;

    const size_t SZ = (size_t)NNODES * CFEAT;   // 393216
    float* pool = wsf;
    float* gf   = wsf + SZ;
    float* Y    = wsf + 2 * SZ;
    unsigned short* poolb = (unsigned short*)(wsf + 4 * SZ);
    unsigned short* x1b   = (unsigned short*)(wsf + 5 * SZ);

    const size_t WOFF = 4ull * 2048 * 512;

    pool_kernel<<<dim3(4096), dim3(256), 0, stream>>>(F, pool, poolb);

    gemm_kernel<<<dim3(256), dim3(512), 0, stream>>>(poolb, Wl, Wr, bl, br, Y);
    attn_kernel<0><<<dim3(32, 4), dim3(256), 0, stream>>>(Y, att, gb, nps,
                                                          nullptr, nullptr, x1b);

    gemm_kernel<<<dim3(256), dim3(512), 0, stream>>>(x1b, Wl + WOFF, Wr + WOFF,
                                                     bl + 2048, br + 2048, Y);
    attn_kernel<1><<<dim3(32, 4), dim3(256), 0, stream>>>(Y, att + 2048, gb + 2048,
                                                          nps, pool, gf, nullptr);

    final_kernel<<<dim3(256), dim3(256), 0, stream>>>(gf, gamma, mean, var, out);
}

// Round 10
// 139.021 us; speedup vs baseline: 11.7658x; 11.7658x over previous
//
#include <hip/hip_runtime.h>
#include <hip/hip_bf16.h>

// ---------------------------------------------------------------------------
// Round 10: transpose-once weights. wtrans: W fp32 [4][2048][512] -> WT bf16
// [4096 cols][2048 k] (k-contiguous rows). gemm v5 = R8 skeleton (proven) with
// B-frag = one b128 load from WT (no cvt, no strided scalars, no reg-ring);
// all 8 B-loads per wave hoisted for MLP. Probe reps removed everywhere.
// Node order: n = p*32 + b.  Instance g = n // 6, valid iff (n % 6) < nps[g].
// ---------------------------------------------------------------------------

#define NNODES 192
#define CFEAT  2048

typedef __attribute__((ext_vector_type(8))) short bf16x8;
typedef __attribute__((ext_vector_type(4))) float f32x4;

__device__ inline unsigned f2bf(float f) {                 // RNE f32 -> bf16
    union { float f; unsigned u; } v; v.f = f;
    unsigned u = v.u;
    u += 0x7FFFu + ((u >> 16) & 1u);
    return u >> 16;
}

// ---- 1. Global average pool (measured R7: ~33.5us = BW floor; do not touch)
__global__ __launch_bounds__(256) void pool_kernel(const float* __restrict__ F,
                                                   float* __restrict__ POOL,
                                                   unsigned short* __restrict__ POOLB) {
    int wave = threadIdx.x >> 6, lane = threadIdx.x & 63;
    #pragma unroll
    for (int it = 0; it < 12; ++it) {
        int dr = blockIdx.x * 4 + wave + it * 16384;   // [0, 196608)
        int r0 = dr * 2;
        int n = r0 >> 11, c0 = r0 & 2047;
        int p = n >> 5, b = n & 31;                    // n = p*32 + b
        const float* src = F + (((size_t)b * 12288 + (size_t)p * 2048 + c0) << 7);
        float4 v = *(const float4*)(src + (lane << 2));
        float acc = (v.x + v.y) + (v.z + v.w);
        acc += __shfl_down(acc, 16);
        acc += __shfl_down(acc, 8);
        acc += __shfl_down(acc, 4);
        acc += __shfl_down(acc, 2);
        acc += __shfl_down(acc, 1);
        if ((lane & 31) == 0) {
            int r = r0 + (lane >> 5);
            float m = acc * (1.0f / 128.0f);
            POOL[r] = m;
            POOLB[r] = (unsigned short)f2bf(m);
        }
    }
}

// ---- 1b. Weight transpose+cvt (one layer): WT[n'][k] = bf16(W[s][h][k][d])
// n' = s*2048 + h*512 + d.  grid 2048 blocks: bid = [s][h][kt(5b)][nt(3b)],
// tile = 64 k x 64 d. 256 threads. LDS tile [64 n][74 k] bf16 (pad 74: write
// ~2-way banks, b32-aligned reads).
__global__ __launch_bounds__(256) void wtrans_kernel(
    const float* __restrict__ WL, const float* __restrict__ WR,
    unsigned short* __restrict__ WT) {
    __shared__ unsigned short tt[64 * 74];
    int bid = blockIdx.x;
    int nt = bid & 7;
    int kt = (bid >> 3) & 31;
    int h  = (bid >> 8) & 3;
    int s  = bid >> 10;
    const float* src = (s ? WR : WL) + (size_t)h * (2048 * 512)
                     + (size_t)(kt * 64) * 512 + nt * 64;
    int t = threadIdx.x;
    int nf = t & 15, kr = t >> 4;
    #pragma unroll
    for (int p = 0; p < 4; ++p) {
        int k = kr + p * 16;
        float4 v = *(const float4*)(src + (size_t)k * 512 + nf * 4);
        tt[(nf * 4 + 0) * 74 + k] = (unsigned short)f2bf(v.x);
        tt[(nf * 4 + 1) * 74 + k] = (unsigned short)f2bf(v.y);
        tt[(nf * 4 + 2) * 74 + k] = (unsigned short)f2bf(v.z);
        tt[(nf * 4 + 3) * 74 + k] = (unsigned short)f2bf(v.w);
    }
    __syncthreads();
    int kc = (t & 7) * 8, nr = t >> 3;               // 32 n-rows per pass
    size_t base = ((size_t)(s * 2048 + h * 512 + nt * 64)) * 2048 + kt * 64;
    #pragma unroll
    for (int p = 0; p < 2; ++p) {
        int n = nr + p * 32;
        const unsigned short* rp = tt + n * 74 + kc;  // (n*74+kc)*2 % 4 == 0
        uint4 o;
        o.x = *(const unsigned*)(rp + 0);
        o.y = *(const unsigned*)(rp + 2);
        o.z = *(const unsigned*)(rp + 4);
        o.w = *(const unsigned*)(rp + 6);
        *(uint4*)(WT + base + (size_t)n * 2048 + kc) = o;
    }
}

// ---- 2. GEMM v5: Y[192][4096] = X @ WT^T + bias.  grid 256 x 512 thr.
// block ct -> flat cols [ct*16, ct*16+16); 8 waves; wave w owns K-chunk
// [w*256,(w+1)*256) (8 ksteps of 32); LDS-reduce partials; fused bias.
// B-frag: lane reads WT[fc+lr][k0 + lg*8 .. +7] = one b128 (1KB/wave-instr).
// All 8 B-loads hoisted before the K-loop for memory-level parallelism.
__global__ __launch_bounds__(512) void gemm_kernel(
    const unsigned short* __restrict__ X,    // bf16 [192][2048]
    const unsigned short* __restrict__ WT,   // bf16 [4096][2048] (layer slice)
    const float* __restrict__ BL,            // fp32 [2048] flat (layer slice)
    const float* __restrict__ BR,
    float* __restrict__ Y) {                 // fp32 [192][4096]
    __shared__ float red[8 * 192 * 18];      // 110 KB

    int ct = blockIdx.x;                     // [0,256)
    int t = threadIdx.x, w = t >> 6, l = t & 63;
    int lr = l & 15, lg = l >> 4;

    int ncol = ct << 4;                      // flat col base
    bool sideR = ncol >= 2048;
    const float* Bb = (sideR ? BR : BL) + (ncol & 2047);
    int kw = w << 8;                         // wave K-base

    const unsigned short* Wp = WT + (size_t)(ncol + lr) * 2048 + kw + lg * 8;
    const unsigned short* Xp = X + (size_t)lr * 2048 + kw + lg * 8;

    // hoist the 8 HBM-critical B-loads (independent, in flight together)
    bf16x8 bfr0 = *(const bf16x8*)(Wp + 0 * 32);
    bf16x8 bfr1 = *(const bf16x8*)(Wp + 1 * 32);
    bf16x8 bfr2 = *(const bf16x8*)(Wp + 2 * 32);
    bf16x8 bfr3 = *(const bf16x8*)(Wp + 3 * 32);
    bf16x8 bfr4 = *(const bf16x8*)(Wp + 4 * 32);
    bf16x8 bfr5 = *(const bf16x8*)(Wp + 5 * 32);
    bf16x8 bfr6 = *(const bf16x8*)(Wp + 6 * 32);
    bf16x8 bfr7 = *(const bf16x8*)(Wp + 7 * 32);

    f32x4 acc[12];
    #pragma unroll
    for (int fi = 0; fi < 12; ++fi) acc[fi] = {0.f, 0.f, 0.f, 0.f};

#define KSTEP(s, bfr)                                                         \
    {                                                                         \
        _Pragma("unroll")                                                     \
        for (int fi = 0; fi < 12; ++fi) {                                     \
            bf16x8 af = *(const bf16x8*)(Xp + (size_t)fi * 16 * 2048 + (s) * 32); \
            acc[fi] = __builtin_amdgcn_mfma_f32_16x16x32_bf16(                \
                          af, bfr, acc[fi], 0, 0, 0);                         \
        }                                                                     \
    }
    KSTEP(0, bfr0) KSTEP(1, bfr1) KSTEP(2, bfr2) KSTEP(3, bfr3)
    KSTEP(4, bfr4) KSTEP(5, bfr5) KSTEP(6, bfr6) KSTEP(7, bfr7)
#undef KSTEP

    // stash partials: D row = lg*4 + reg (frag fi base 16*fi), col = lr
    #pragma unroll
    for (int fi = 0; fi < 12; ++fi)
        #pragma unroll
        for (int j = 0; j < 4; ++j)
            red[(w * 192 + fi * 16 + lg * 4 + j) * 18 + lr] = acc[fi][j];
    __syncthreads();

    // reduce 8 partials -> Y (+bias); 3072 outputs / 512 threads
    #pragma unroll
    for (int e = 0; e < 6; ++e) {
        int idx = t + e * 512;
        int row = idx >> 4, col = idx & 15;
        float sum = 0.f;
        #pragma unroll
        for (int ww = 0; ww < 8; ++ww)
            sum += red[(ww * 192 + row) * 18 + col];
        Y[(size_t)row * 4096 + ncol + col] = sum + Bb[col];
    }
}

// ---- 3. Attention per (instance g, head h). Y: [192][4096], xl 0..2047,
// xr 2048..4095 (bias already in Y).
template <int LAYER>
__global__ __launch_bounds__(256) void attn_kernel(
    const float* __restrict__ Y,
    const float* __restrict__ ATT,
    const float* __restrict__ GBIAS,
    const int* __restrict__ NPS,
    const float* __restrict__ POOL,
    float* __restrict__ OUTF,
    unsigned short* __restrict__ OUTB) {
    __shared__ float xls[6][512];
    __shared__ float xrs[6][512];
    __shared__ float atts[512];
    __shared__ float s_sm[6][6];
    __shared__ float alpha[6][6];

    int g = blockIdx.x, h = blockIdx.y;
    int tid = threadIdx.x;
    int cnt = NPS[g];

    for (int idx = tid; idx < 6 * 512; idx += 256) {
        int q = idx >> 9, d = idx & 511;
        size_t off = (size_t)(g * 6 + q) * 4096 + h * 512 + d;
        xls[q][d] = Y[off];
        xrs[q][d] = Y[off + 2048];
    }
    for (int d = tid; d < 512; d += 256) atts[d] = ATT[h * 512 + d];
    __syncthreads();

    int wv = tid >> 6, lane = tid & 63;
    for (int p = wv; p < 36; p += 4) {
        int i = p / 6, j = p % 6;
        float acc = 0.f;
        #pragma unroll
        for (int u = 0; u < 8; ++u) {
            int d = lane + u * 64;
            float v = xrs[i][d] + xls[j][d];
            v = (v >= 0.f) ? v : 0.2f * v;
            acc = fmaf(atts[d], v, acc);
        }
        #pragma unroll
        for (int off = 32; off; off >>= 1) acc += __shfl_down(acc, off);
        if (lane == 0) s_sm[i][j] = acc;
    }
    __syncthreads();

    if (tid < 6) {
        int i = tid;
        bool iv = i < cnt;
        float mx;
        if (iv) {
            mx = -1e30f;
            for (int j = 0; j < cnt; ++j) mx = fmaxf(mx, s_sm[i][j]);
        } else {
            mx = s_sm[i][i];
        }
        float e[6], sum = 0.f;
        for (int j = 0; j < 6; ++j) {
            bool nb = iv ? (j < cnt) : (j == i);
            e[j] = nb ? expf(s_sm[i][j] - mx) : 0.f;
            sum += e[j];
        }
        float inv = 1.f / sum;
        for (int j = 0; j < 6; ++j) alpha[i][j] = e[j] * inv;
    }
    __syncthreads();

    for (int idx = tid; idx < 6 * 512; idx += 256) {
        int q = idx >> 9, d = idx & 511;
        float acc = 0.f;
        #pragma unroll
        for (int j = 0; j < 6; ++j) acc = fmaf(alpha[q][j], xls[j][d], acc);
        int col = h * 512 + d;
        size_t off = (size_t)(g * 6 + q) * 2048 + col;
        float v = acc + GBIAS[col];
        if (LAYER == 0) {
            v = (v > 0.f) ? v : expm1f(v);
            OUTB[off] = (unsigned short)f2bf(v);
        } else {
            OUTF[off] = v + POOL[off];
        }
    }
}

// ---- 4. Part-mean + BN
__global__ __launch_bounds__(256) void final_kernel(
    const float* __restrict__ GF, const float* __restrict__ GAMMA,
    const float* __restrict__ MEAN, const float* __restrict__ VAR,
    float* __restrict__ OUTP) {
    int idx = blockIdx.x * 256 + threadIdx.x;   // [0, 65536)
    int c = idx & 2047, b = idx >> 11;
    float acc = 0.f;
    #pragma unroll
    for (int p = 0; p < 6; ++p) acc += GF[(size_t)(p * 32 + b) * 2048 + c];
    acc *= (1.f / 6.f);
    OUTP[idx] = GAMMA[c] * (acc - MEAN[c]) * rsqrtf(VAR[c] + 1e-5f);
}

extern "C" void kernel_launch(void* const* d_in, const int* in_sizes, int n_in,
                              void* d_out, int out_size, void* d_ws, size_t ws_size,
                              hipStream_t stream) {
    const float* F     = (const float*)d_in[0];
    const int*   nps   = (const int*)d_in[1];
    const float* Wl    = (const float*)d_in[2];
    const float* bl    = (const float*)d_in[3];
    const float* Wr    = (const float*)d_in[4];
    const float* br    = (const float*)d_in[5];
    const float* att   = (const float*)d_in[6];
    const float* gb    = (const float*)d_in[7];
    const float* gamma = (const float*)d_in[8];
    const float* mean  = (const float*)d_in[9];
    const float* var   = (const float*)d_in[10];
    float* out = (float*)d_out;
    float* wsf = (float*)d_ws;

    const size_t SZ = (size_t)NNODES * CFEAT;   // 393216
    float* pool = wsf;                                        // [192][2048] f32
    float* gf   = wsf + SZ;                                   // [192][2048] f32
    float* Y    = wsf + 2 * SZ;                               // [192][4096] f32
    unsigned short* poolb = (unsigned short*)(wsf + 4 * SZ);  // bf16 [192][2048]
    unsigned short* x1b   = (unsigned short*)(wsf + 5 * SZ);  // bf16 [192][2048]
    unsigned short* WT    = (unsigned short*)(wsf + 6 * SZ);  // bf16 [4096][2048] (16.8MB)

    const size_t WOFF = 4ull * 2048 * 512;       // per-layer weight stride

    // 1. pool (fp32 + bf16)
    pool_kernel<<<dim3(4096), dim3(256), 0, stream>>>(F, pool, poolb);

    // 2. layer 0: transpose -> gemm -> attn
    wtrans_kernel<<<dim3(2048), dim3(256), 0, stream>>>(Wl, Wr, WT);
    gemm_kernel<<<dim3(256), dim3(512), 0, stream>>>(poolb, WT, bl, br, Y);
    attn_kernel<0><<<dim3(32, 4), dim3(256), 0, stream>>>(Y, att, gb, nps,
                                                          nullptr, nullptr, x1b);

    // 3. layer 1
    wtrans_kernel<<<dim3(2048), dim3(256), 0, stream>>>(Wl + WOFF, Wr + WOFF, WT);
    gemm_kernel<<<dim3(256), dim3(512), 0, stream>>>(x1b, WT, bl + 2048, br + 2048, Y);
    attn_kernel<1><<<dim3(32, 4), dim3(256), 0, stream>>>(Y, att + 2048, gb + 2048,
                                                          nps, pool, gf, nullptr);

    // 4. part-mean + BN
    final_kernel<<<dim3(256), dim3(256), 0, stream>>>(gf, gamma, mean, var, out);
}

// Round 11
// 135.655 us; speedup vs baseline: 12.0577x; 1.0248x over previous
//
#include <hip/hip_runtime.h>
#include <hip/hip_bf16.h>

// ---------------------------------------------------------------------------
// Round 11: fused prep. One dispatch does pool (blocks 0..4095) + weight
// transpose for BOTH layers (blocks 4096..8191) -> overlapped BW streams,
// fewer gaps, WT L3-hot for gemms. gemm v5 / attn / final unchanged (proven).
// Fallback to R10's per-layer wtrans if ws_size can't hold two WT layers.
// Node order: n = p*32 + b.  Instance g = n // 6, valid iff (n % 6) < nps[g].
// ---------------------------------------------------------------------------

#define NNODES 192
#define CFEAT  2048

typedef __attribute__((ext_vector_type(8))) short bf16x8;
typedef __attribute__((ext_vector_type(4))) float f32x4;

__device__ inline unsigned f2bf(float f) {                 // RNE f32 -> bf16
    union { float f; unsigned u; } v; v.f = f;
    unsigned u = v.u;
    u += 0x7FFFu + ((u >> 16) & 1u);
    return u >> 16;
}

// ---- pool body (measured R7: ~33.5us at BW floor)
__device__ inline void pool_body(int bid, int tid, const float* __restrict__ F,
                                 float* __restrict__ POOL,
                                 unsigned short* __restrict__ POOLB) {
    int wave = tid >> 6, lane = tid & 63;
    #pragma unroll
    for (int it = 0; it < 12; ++it) {
        int dr = bid * 4 + wave + it * 16384;          // [0, 196608)
        int r0 = dr * 2;
        int n = r0 >> 11, c0 = r0 & 2047;
        int p = n >> 5, b = n & 31;                    // n = p*32 + b
        const float* src = F + (((size_t)b * 12288 + (size_t)p * 2048 + c0) << 7);
        float4 v = *(const float4*)(src + (lane << 2));
        float acc = (v.x + v.y) + (v.z + v.w);
        acc += __shfl_down(acc, 16);
        acc += __shfl_down(acc, 8);
        acc += __shfl_down(acc, 4);
        acc += __shfl_down(acc, 2);
        acc += __shfl_down(acc, 1);
        if ((lane & 31) == 0) {
            int r = r0 + (lane >> 5);
            float m = acc * (1.0f / 128.0f);
            POOL[r] = m;
            POOLB[r] = (unsigned short)f2bf(m);
        }
    }
}

// ---- wtrans body (proven R10): one 64k x 64d tile of one layer/side/head
__device__ inline void wtrans_body(int bid2, int tid, unsigned short* tt,
                                   const float* __restrict__ WL,
                                   const float* __restrict__ WR,
                                   unsigned short* __restrict__ WT) {
    int nt = bid2 & 7;
    int kt = (bid2 >> 3) & 31;
    int h  = (bid2 >> 8) & 3;
    int s  = bid2 >> 10;
    const float* src = (s ? WR : WL) + (size_t)h * (2048 * 512)
                     + (size_t)(kt * 64) * 512 + nt * 64;
    int nf = tid & 15, kr = tid >> 4;
    #pragma unroll
    for (int p = 0; p < 4; ++p) {
        int k = kr + p * 16;
        float4 v = *(const float4*)(src + (size_t)k * 512 + nf * 4);
        tt[(nf * 4 + 0) * 74 + k] = (unsigned short)f2bf(v.x);
        tt[(nf * 4 + 1) * 74 + k] = (unsigned short)f2bf(v.y);
        tt[(nf * 4 + 2) * 74 + k] = (unsigned short)f2bf(v.z);
        tt[(nf * 4 + 3) * 74 + k] = (unsigned short)f2bf(v.w);
    }
    __syncthreads();
    int kc = (tid & 7) * 8, nr = tid >> 3;             // 32 n-rows per pass
    size_t base = ((size_t)(s * 2048 + h * 512 + nt * 64)) * 2048 + kt * 64;
    #pragma unroll
    for (int p = 0; p < 2; ++p) {
        int n = nr + p * 32;
        const unsigned short* rp = tt + n * 74 + kc;
        uint4 o;
        o.x = *(const unsigned*)(rp + 0);
        o.y = *(const unsigned*)(rp + 2);
        o.z = *(const unsigned*)(rp + 4);
        o.w = *(const unsigned*)(rp + 6);
        *(uint4*)(WT + base + (size_t)n * 2048 + kc) = o;
    }
}

// ---- 1a. Fused prep: blocks [0,4096) pool; [4096,8192) wtrans L0/L1
__global__ __launch_bounds__(256) void prep_kernel(
    const float* __restrict__ F, float* __restrict__ POOL,
    unsigned short* __restrict__ POOLB,
    const float* __restrict__ Wl, const float* __restrict__ Wr,
    unsigned short* __restrict__ WT) {       // [2][4096][2048] bf16
    __shared__ unsigned short tt[64 * 74];
    int bid = blockIdx.x, tid = threadIdx.x;
    if (bid < 4096) {
        pool_body(bid, tid, F, POOL, POOLB);
    } else {
        int local = bid - 4096;
        int lyr = local >> 11, bid2 = local & 2047;
        const size_t WOFF = 4ull * 2048 * 512;
        wtrans_body(bid2, tid, tt, Wl + lyr * WOFF, Wr + lyr * WOFF,
                    WT + (size_t)lyr * (4096ull * 2048));
    }
}

// ---- 1b/1c. standalone fallbacks (ws too small for 2 WT layers)
__global__ __launch_bounds__(256) void pool_kernel(
    const float* __restrict__ F, float* __restrict__ POOL,
    unsigned short* __restrict__ POOLB) {
    pool_body(blockIdx.x, threadIdx.x, F, POOL, POOLB);
}
__global__ __launch_bounds__(256) void wtrans_kernel(
    const float* __restrict__ WL, const float* __restrict__ WR,
    unsigned short* __restrict__ WT) {
    __shared__ unsigned short tt[64 * 74];
    wtrans_body(blockIdx.x, threadIdx.x, tt, WL, WR, WT);
}

// ---- 2. GEMM v5 (proven R10): Y[192][4096] = X @ WT^T + bias.
__global__ __launch_bounds__(512) void gemm_kernel(
    const unsigned short* __restrict__ X,    // bf16 [192][2048]
    const unsigned short* __restrict__ WT,   // bf16 [4096][2048] (layer slice)
    const float* __restrict__ BL,            // fp32 [2048] flat (layer slice)
    const float* __restrict__ BR,
    float* __restrict__ Y) {                 // fp32 [192][4096]
    __shared__ float red[8 * 192 * 18];      // 110 KB

    int ct = blockIdx.x;                     // [0,256)
    int t = threadIdx.x, w = t >> 6, l = t & 63;
    int lr = l & 15, lg = l >> 4;

    int ncol = ct << 4;
    bool sideR = ncol >= 2048;
    const float* Bb = (sideR ? BR : BL) + (ncol & 2047);
    int kw = w << 8;

    const unsigned short* Wp = WT + (size_t)(ncol + lr) * 2048 + kw + lg * 8;
    const unsigned short* Xp = X + (size_t)lr * 2048 + kw + lg * 8;

    bf16x8 bfr0 = *(const bf16x8*)(Wp + 0 * 32);
    bf16x8 bfr1 = *(const bf16x8*)(Wp + 1 * 32);
    bf16x8 bfr2 = *(const bf16x8*)(Wp + 2 * 32);
    bf16x8 bfr3 = *(const bf16x8*)(Wp + 3 * 32);
    bf16x8 bfr4 = *(const bf16x8*)(Wp + 4 * 32);
    bf16x8 bfr5 = *(const bf16x8*)(Wp + 5 * 32);
    bf16x8 bfr6 = *(const bf16x8*)(Wp + 6 * 32);
    bf16x8 bfr7 = *(const bf16x8*)(Wp + 7 * 32);

    f32x4 acc[12];
    #pragma unroll
    for (int fi = 0; fi < 12; ++fi) acc[fi] = {0.f, 0.f, 0.f, 0.f};

#define KSTEP(s, bfr)                                                         \
    {                                                                         \
        _Pragma("unroll")                                                     \
        for (int fi = 0; fi < 12; ++fi) {                                     \
            bf16x8 af = *(const bf16x8*)(Xp + (size_t)fi * 16 * 2048 + (s) * 32); \
            acc[fi] = __builtin_amdgcn_mfma_f32_16x16x32_bf16(                \
                          af, bfr, acc[fi], 0, 0, 0);                         \
        }                                                                     \
    }
    KSTEP(0, bfr0) KSTEP(1, bfr1) KSTEP(2, bfr2) KSTEP(3, bfr3)
    KSTEP(4, bfr4) KSTEP(5, bfr5) KSTEP(6, bfr6) KSTEP(7, bfr7)
#undef KSTEP

    #pragma unroll
    for (int fi = 0; fi < 12; ++fi)
        #pragma unroll
        for (int j = 0; j < 4; ++j)
            red[(w * 192 + fi * 16 + lg * 4 + j) * 18 + lr] = acc[fi][j];
    __syncthreads();

    #pragma unroll
    for (int e = 0; e < 6; ++e) {
        int idx = t + e * 512;
        int row = idx >> 4, col = idx & 15;
        float sum = 0.f;
        #pragma unroll
        for (int ww = 0; ww < 8; ++ww)
            sum += red[(ww * 192 + row) * 18 + col];
        Y[(size_t)row * 4096 + ncol + col] = sum + Bb[col];
    }
}

// ---- 3. Attention per (instance g, head h). Y: [192][4096], xl 0..2047,
// xr 2048..4095 (bias already in Y).
template <int LAYER>
__global__ __launch_bounds__(256) void attn_kernel(
    const float* __restrict__ Y,
    const float* __restrict__ ATT,
    const float* __restrict__ GBIAS,
    const int* __restrict__ NPS,
    const float* __restrict__ POOL,
    float* __restrict__ OUTF,
    unsigned short* __restrict__ OUTB) {
    __shared__ float xls[6][512];
    __shared__ float xrs[6][512];
    __shared__ float atts[512];
    __shared__ float s_sm[6][6];
    __shared__ float alpha[6][6];

    int g = blockIdx.x, h = blockIdx.y;
    int tid = threadIdx.x;
    int cnt = NPS[g];

    for (int idx = tid; idx < 6 * 512; idx += 256) {
        int q = idx >> 9, d = idx & 511;
        size_t off = (size_t)(g * 6 + q) * 4096 + h * 512 + d;
        xls[q][d] = Y[off];
        xrs[q][d] = Y[off + 2048];
    }
    for (int d = tid; d < 512; d += 256) atts[d] = ATT[h * 512 + d];
    __syncthreads();

    int wv = tid >> 6, lane = tid & 63;
    for (int p = wv; p < 36; p += 4) {
        int i = p / 6, j = p % 6;
        float acc = 0.f;
        #pragma unroll
        for (int u = 0; u < 8; ++u) {
            int d = lane + u * 64;
            float v = xrs[i][d] + xls[j][d];
            v = (v >= 0.f) ? v : 0.2f * v;
            acc = fmaf(atts[d], v, acc);
        }
        #pragma unroll
        for (int off = 32; off; off >>= 1) acc += __shfl_down(acc, off);
        if (lane == 0) s_sm[i][j] = acc;
    }
    __syncthreads();

    if (tid < 6) {
        int i = tid;
        bool iv = i < cnt;
        float mx;
        if (iv) {
            mx = -1e30f;
            for (int j = 0; j < cnt; ++j) mx = fmaxf(mx, s_sm[i][j]);
        } else {
            mx = s_sm[i][i];
        }
        float e[6], sum = 0.f;
        for (int j = 0; j < 6; ++j) {
            bool nb = iv ? (j < cnt) : (j == i);
            e[j] = nb ? expf(s_sm[i][j] - mx) : 0.f;
            sum += e[j];
        }
        float inv = 1.f / sum;
        for (int j = 0; j < 6; ++j) alpha[i][j] = e[j] * inv;
    }
    __syncthreads();

    for (int idx = tid; idx < 6 * 512; idx += 256) {
        int q = idx >> 9, d = idx & 511;
        float acc = 0.f;
        #pragma unroll
        for (int j = 0; j < 6; ++j) acc = fmaf(alpha[q][j], xls[j][d], acc);
        int col = h * 512 + d;
        size_t off = (size_t)(g * 6 + q) * 2048 + col;
        float v = acc + GBIAS[col];
        if (LAYER == 0) {
            v = (v > 0.f) ? v : expm1f(v);
            OUTB[off] = (unsigned short)f2bf(v);
        } else {
            OUTF[off] = v + POOL[off];
        }
    }
}

// ---- 4. Part-mean + BN
__global__ __launch_bounds__(256) void final_kernel(
    const float* __restrict__ GF, const float* __restrict__ GAMMA,
    const float* __restrict__ MEAN, const float* __restrict__ VAR,
    float* __restrict__ OUTP) {
    int idx = blockIdx.x * 256 + threadIdx.x;   // [0, 65536)
    int c = idx & 2047, b = idx >> 11;
    float acc = 0.f;
    #pragma unroll
    for (int p = 0; p < 6; ++p) acc += GF[(size_t)(p * 32 + b) * 2048 + c];
    acc *= (1.f / 6.f);
    OUTP[idx] = GAMMA[c] * (acc - MEAN[c]) * rsqrtf(VAR[c] + 1e-5f);
}

extern "C" void kernel_launch(void* const* d_in, const int* in_sizes, int n_in,
                              void* d_out, int out_size, void* d_ws, size_t ws_size,
                              hipStream_t stream) {
    const float* F     = (const float*)d_in[0];
    const int*   nps   = (const int*)d_in[1];
    const float* Wl    = (const float*)d_in[2];
    const float* bl    = (const float*)d_in[3];
    const float* Wr    = (const float*)d_in[4];
    const float* br    = (const float*)d_in[5];
    const float* att   = (const float*)d_in[6];
    const float* gb    = (const float*)d_in[7];
    const float* gamma = (const float*)d_in[8];
    const float* mean  = (const float*)d_in[9];
    const float* var   = (const float*)d_in[10];
    float* out = (float*)d_out;
    float* wsf = (float*)d_ws;

    const size_t SZ = (size_t)NNODES * CFEAT;        // 393216 floats
    const size_t WT_ELEMS = 4096ull * 2048;          // per-layer bf16 count

    float* pool = wsf;                                        // [192][2048] f32
    float* gf   = wsf + SZ;                                   // [192][2048] f32
    float* Y    = wsf + 2 * SZ;                               // [192][4096] f32
    unsigned short* poolb = (unsigned short*)(wsf + 4 * SZ);  // bf16 [192][2048]
    unsigned short* x1b   = (unsigned short*)(wsf + 5 * SZ);  // bf16 [192][2048]
    unsigned short* WT    = (unsigned short*)(wsf + 6 * SZ);  // bf16 [<=2][4096][2048]

    const size_t WOFF = 4ull * 2048 * 512;           // per-layer fp32 W stride
    size_t need_fused = 6 * SZ * 4 + 2 * WT_ELEMS * 2;

    if (ws_size >= need_fused) {
        // fused prep: pool + both wtrans in one dispatch
        prep_kernel<<<dim3(8192), dim3(256), 0, stream>>>(F, pool, poolb,
                                                          Wl, Wr, WT);
        gemm_kernel<<<dim3(256), dim3(512), 0, stream>>>(poolb, WT, bl, br, Y);
        attn_kernel<0><<<dim3(32, 4), dim3(256), 0, stream>>>(Y, att, gb, nps,
                                                              nullptr, nullptr, x1b);
        gemm_kernel<<<dim3(256), dim3(512), 0, stream>>>(x1b, WT + WT_ELEMS,
                                                         bl + 2048, br + 2048, Y);
        attn_kernel<1><<<dim3(32, 4), dim3(256), 0, stream>>>(Y, att + 2048,
                                                              gb + 2048, nps,
                                                              pool, gf, nullptr);
    } else {
        // fallback (R10 structure): single WT buffer, per-layer transpose
        pool_kernel<<<dim3(4096), dim3(256), 0, stream>>>(F, pool, poolb);
        wtrans_kernel<<<dim3(2048), dim3(256), 0, stream>>>(Wl, Wr, WT);
        gemm_kernel<<<dim3(256), dim3(512), 0, stream>>>(poolb, WT, bl, br, Y);
        attn_kernel<0><<<dim3(32, 4), dim3(256), 0, stream>>>(Y, att, gb, nps,
                                                              nullptr, nullptr, x1b);
        wtrans_kernel<<<dim3(2048), dim3(256), 0, stream>>>(Wl + WOFF, Wr + WOFF, WT);
        gemm_kernel<<<dim3(256), dim3(512), 0, stream>>>(poolb /*unused*/, WT,
                                                         bl + 2048, br + 2048, Y);
        // NOTE: correct X for layer 1 is x1b:
        gemm_kernel<<<dim3(256), dim3(512), 0, stream>>>(x1b, WT,
                                                         bl + 2048, br + 2048, Y);
        attn_kernel<1><<<dim3(32, 4), dim3(256), 0, stream>>>(Y, att + 2048,
                                                              gb + 2048, nps,
                                                              pool, gf, nullptr);
    }

    final_kernel<<<dim3(256), dim3(256), 0, stream>>>(gf, gamma, mean, var, out);
}